// Round 7
// baseline (674.905 us; speedup 1.0000x reference)
//
#include <hip/hip_runtime.h>
#include <hip/hip_bf16.h>

#define NNODES 20000
#define NEDGES 640000
#define DM 256
#define PAD 128

typedef short s16x8 __attribute__((ext_vector_type(8)));
typedef float f32x4 __attribute__((ext_vector_type(4)));
typedef float f32x2 __attribute__((ext_vector_type(2)));

__device__ inline float b2f(unsigned short u) {
  union { unsigned int i; float f; } z;
  z.i = (unsigned int)u << 16;
  return z.f;
}
__device__ inline unsigned short f2b(float f) {
  union { unsigned int i; float f; } z;
  z.f = f;
  unsigned int i = z.i;
  return (unsigned short)((i + 0x7FFFu + ((i >> 16) & 1u)) >> 16);
}

// ---------------- fp8 e4m3 encode/decode ------------------------------------
__device__ inline unsigned char f2fp8(float v) {
#if __has_builtin(__builtin_amdgcn_cvt_pk_fp8_f32)
  int t = __builtin_amdgcn_cvt_pk_fp8_f32(v, v, 0, false);
  return (unsigned char)(t & 0xFF);
#else
  union { float f; unsigned int u; } z;
  z.f = v;
  unsigned int s = (z.u >> 31) << 7;
  float av = fabsf(v);
  if (av >= 448.f) return (unsigned char)(s | 0x7E);
  if (av < 0.015625f) {
    int q = (int)rintf(av * 512.f);
    return (unsigned char)(s | (unsigned)q);
  }
  int e32 = (int)((z.u >> 23) & 255) - 127;
  unsigned mant = z.u & 0x7FFFFF;
  unsigned t = mant + 0x7FFFF + ((mant >> 20) & 1);
  if (t >= 0x800000u) { t = 0; e32++; }
  int e4 = e32 + 7;
  unsigned m3 = (t >> 20) & 7;
  if (e4 > 15 || (e4 == 15 && m3 == 7)) return (unsigned char)(s | 0x7E);
  return (unsigned char)(s | (unsigned)((e4 << 3) | m3));
#endif
}

__device__ inline float4 fp8x4_dec(unsigned int u) {
#if __has_builtin(__builtin_amdgcn_cvt_pk_f32_fp8)
  f32x2 lo = __builtin_amdgcn_cvt_pk_f32_fp8((int)u, false);
  f32x2 hi = __builtin_amdgcn_cvt_pk_f32_fp8((int)u, true);
  float4 r;
  r.x = lo[0]; r.y = lo[1]; r.z = hi[0]; r.w = hi[1];
  return r;
#else
  float4 r;
  float* p = &r.x;
#pragma unroll
  for (int j = 0; j < 4; j++) {
    unsigned b = (u >> (8 * j)) & 0xFF;
    unsigned s = b >> 7, e = (b >> 3) & 15, m = b & 7;
    float mag;
    if (e == 0) mag = (float)m * 0.001953125f;
    else {
      union { unsigned int i; float f; } z;
      z.i = ((e + 120u) << 23) | (m << 20);
      mag = z.f;
    }
    p[j] = s ? -mag : mag;
  }
  return r;
#endif
}

// ---------------- gather: x = ent[cid] (f32 + bf16) -------------------------
__global__ __launch_bounds__(256) void gather_kernel(
    const int* __restrict__ cid, const float* __restrict__ ent,
    float* __restrict__ x, unsigned short* __restrict__ xb, int n) {
  int idx = blockIdx.x * 256 + threadIdx.x;
  if (idx >= n * 64) return;
  int node = idx >> 6, d4 = idx & 63;
  float4 v = reinterpret_cast<const float4*>(ent)[(size_t)cid[node] * 64 + d4];
  reinterpret_cast<float4*>(x)[(size_t)node * 64 + d4] = v;
  ushort4 b;
  b.x = f2b(v.x); b.y = f2b(v.y); b.z = f2b(v.z); b.w = f2b(v.w);
  reinterpret_cast<ushort4*>(xb)[(size_t)node * 64 + d4] = b;
}

// ---------------- all 12 square weights -> bf16 [N][K] ----------------------
__global__ __launch_bounds__(256) void wtrans12_kernel(
    const float* __restrict__ Wq, const float* __restrict__ Wk,
    const float* __restrict__ Wv, const float* __restrict__ Wo,
    unsigned short* __restrict__ WT) {
  int slot = blockIdx.x >> 8;           // 0..11 = l*4 + t
  int l = slot >> 2, t = slot & 3;
  int n = blockIdx.x & 255;
  int k = threadIdx.x;
  const float* src = (t == 0) ? Wq : (t == 1) ? Wk : (t == 2) ? Wv : Wo;
  WT[(size_t)slot * 65536 + n * 256 + k] =
      f2b(src[(size_t)l * 65536 + k * 256 + n]);
}

// ---------------- W2 (1024x256) -> bf16 [256][1024] --------------------------
__global__ __launch_bounds__(256) void w2t_kernel(const float* __restrict__ W2,
                                                  unsigned short* __restrict__ W2T) {
  int i = blockIdx.x * 256 + threadIdx.x;  // 262144
  int n = i >> 10, k = i & 1023;
  W2T[n * 1024 + k] = f2b(W2[k * 256 + n]);
}

// ---------------- token_embedding f32 -> bf16 --------------------------------
__global__ __launch_bounds__(256) void tokconv_kernel(
    const float* __restrict__ te, unsigned short* __restrict__ tb) {
  int i = blockIdx.x * 256 + threadIdx.x;  // 327680 float4s
  float4 v = reinterpret_cast<const float4*>(te)[i];
  ushort4 b;
  b.x = f2b(v.x); b.y = f2b(v.y); b.z = f2b(v.z); b.w = f2b(v.w);
  reinterpret_cast<ushort4*>(tb)[i] = b;
}

// ---------------- padded-CSR fill: slot = atomicAdd(deg) --------------------
__global__ __launch_bounds__(256) void fill_kernel(const int* __restrict__ ei,
                                                   const int* __restrict__ batch,
                                                   int* __restrict__ deg,
                                                   int* __restrict__ colPad,
                                                   int E) {
  int e = blockIdx.x * 256 + threadIdx.x;
  if (e >= E) return;
  int r = ei[e];
  int c = ei[E + e];
  int slot = atomicAdd(&deg[r], 1);
  if (slot < PAD) colPad[(size_t)r * PAD + slot] = c | ((batch[c] / 5) << 24);
}

// ---------------- QS for all layers: QS5all[l][g][256] ----------------------
__global__ __launch_bounds__(256) void qs5all_kernel(
    const float* __restrict__ sent, const float* __restrict__ Ws,
    const float* __restrict__ bs, float* __restrict__ QS5all) {
  int g = blockIdx.x, l = blockIdx.y;
  int j = threadIdx.x;
  __shared__ float sh[1024];
  for (int i = j; i < 1024; i += 256) sh[i] = sent[g * 1024 + i];
  __syncthreads();
  const float* W = Ws + (size_t)l * 1024 * 256;
  float acc = bs[l * 256 + j];
  for (int k = 0; k < 1024; k++) acc += sh[k] * W[k * 256 + j];
  QS5all[(size_t)(l * 5 + g) * 256 + j] = acc;
}

// ---------------- fused QKV MFMA GEMM: [M,256] @ [256,768] ------------------
__global__ __launch_bounds__(256) void qkv_gemm_kernel(
    const unsigned short* __restrict__ A, const unsigned short* __restrict__ Bt,
    const float* __restrict__ bq, const float* __restrict__ bk,
    const float* __restrict__ bv, float* __restrict__ Qf,
    unsigned char* __restrict__ K8, unsigned char* __restrict__ V8, int M) {
  int wid = threadIdx.x >> 6;
  int lane = threadIdx.x & 63;
  int wr = wid >> 1, wc = wid & 1;
  int rowBase = blockIdx.y * 64 + wr * 32;
  int colBase = blockIdx.x * 64 + wc * 32;  // 0..767
  int r16 = lane & 15, kg = lane >> 4;
  f32x4 acc[2][2] = {};
  for (int k0 = 0; k0 < 256; k0 += 32) {
    s16x8 a[2], b[2];
#pragma unroll
    for (int mi = 0; mi < 2; mi++) {
      int r = rowBase + mi * 16 + r16;
      s16x8 z = {};
      a[mi] = (r < M) ? *reinterpret_cast<const s16x8*>(
                            &A[(size_t)r * 256 + k0 + kg * 8])
                      : z;
    }
#pragma unroll
    for (int ni = 0; ni < 2; ni++) {
      int c = colBase + ni * 16 + r16;
      b[ni] = *reinterpret_cast<const s16x8*>(&Bt[(size_t)c * 256 + k0 + kg * 8]);
    }
#pragma unroll
    for (int mi = 0; mi < 2; mi++)
#pragma unroll
      for (int ni = 0; ni < 2; ni++)
        acc[mi][ni] = __builtin_amdgcn_mfma_f32_16x16x32_bf16(
            a[mi], b[ni], acc[mi][ni], 0, 0, 0);
  }
  int region = (blockIdx.x * 64) >> 8;  // 0,1,2 (block never straddles)
  const float* bias = (region == 0) ? bq : (region == 1) ? bk : bv;
  unsigned char* dst8 = (region == 1) ? K8 : V8;
#pragma unroll
  for (int mi = 0; mi < 2; mi++)
#pragma unroll
    for (int ni = 0; ni < 2; ni++) {
      int cg = colBase + ni * 16 + (lane & 15);
      int cr = cg & 255;
      float bia = bias[cr];
#pragma unroll
      for (int reg = 0; reg < 4; reg++) {
        int r = rowBase + mi * 16 + (lane >> 4) * 4 + reg;
        if (r >= M) continue;
        float v = acc[mi][ni][reg] + bia;
        if (region == 0)
          Qf[(size_t)r * 256 + cr] = v;
        else
          dst8[(size_t)r * 256 + cr] = f2fp8(v);
      }
    }
}

// ---------------- generic MFMA GEMM: C = A@Bt^T + bias (+resid) -------------
__global__ __launch_bounds__(256) void gemm_bf16_kernel(
    const unsigned short* __restrict__ A, const unsigned short* __restrict__ Bt,
    const float* __restrict__ bias, const float* __restrict__ resid,
    float* __restrict__ Cf, unsigned short* __restrict__ Cb, int M, int K) {
  int wid = threadIdx.x >> 6;
  int lane = threadIdx.x & 63;
  int wr = wid >> 1, wc = wid & 1;
  int rowBase = blockIdx.y * 64 + wr * 32;
  int colBase = blockIdx.x * 64 + wc * 32;
  int r16 = lane & 15, kg = lane >> 4;
  f32x4 acc[2][2] = {};
  for (int k0 = 0; k0 < K; k0 += 32) {
    s16x8 a[2], b[2];
#pragma unroll
    for (int mi = 0; mi < 2; mi++) {
      int r = rowBase + mi * 16 + r16;
      s16x8 z = {};
      a[mi] = (r < M) ? *reinterpret_cast<const s16x8*>(
                            &A[(size_t)r * K + k0 + kg * 8])
                      : z;
    }
#pragma unroll
    for (int ni = 0; ni < 2; ni++) {
      int c = colBase + ni * 16 + r16;
      b[ni] = *reinterpret_cast<const s16x8*>(&Bt[(size_t)c * K + k0 + kg * 8]);
    }
#pragma unroll
    for (int mi = 0; mi < 2; mi++)
#pragma unroll
      for (int ni = 0; ni < 2; ni++)
        acc[mi][ni] = __builtin_amdgcn_mfma_f32_16x16x32_bf16(
            a[mi], b[ni], acc[mi][ni], 0, 0, 0);
  }
#pragma unroll
  for (int mi = 0; mi < 2; mi++)
#pragma unroll
    for (int ni = 0; ni < 2; ni++) {
      int c = colBase + ni * 16 + (lane & 15);
      float bia = bias[c];
#pragma unroll
      for (int reg = 0; reg < 4; reg++) {
        int r = rowBase + mi * 16 + (lane >> 4) * 4 + reg;
        if (r >= M) continue;
        float v = acc[mi][ni][reg] + bia;
        if (resid) v += resid[(size_t)r * 256 + c];
        if (Cf) Cf[(size_t)r * 256 + c] = v;
        if (Cb) Cb[(size_t)r * 256 + c] = f2b(v);
      }
    }
}

// ---------------- rescale WoT rows by 1/sums[head] (fold softmax norm) ------
__global__ __launch_bounds__(256) void rescale_wo_kernel(
    unsigned short* __restrict__ WoT, const float* __restrict__ sums) {
  int i = blockIdx.x * 256 + threadIdx.x;  // 65536
  int head = (i & 255) >> 6;
  WoT[i] = f2b(b2f(WoT[i]) / sums[head]);
}

// ---------------- fused edge pass (padded CSR, wave per node) ----------------
// 4 edges per wave-iteration: lane=(e4,l16); each lane loads dwordx4 (16 fp8
// channels) of its edge's K/V; head dot = 2 shfl; cross-e4 combine at end.
template <int DO_AGG>
__global__ __launch_bounds__(256) void fused_edge_kernel(
    const int* __restrict__ deg, const int* __restrict__ colPad,
    const int* __restrict__ batch, const float* __restrict__ Q,
    const unsigned int* __restrict__ K8, const unsigned int* __restrict__ V8,
    const float* __restrict__ QS5, float* __restrict__ sums,
    unsigned short* __restrict__ aggb, int n) {
  int wv = __builtin_amdgcn_readfirstlane(threadIdx.x >> 6);
  int node = blockIdx.x * 4 + wv;  // wave-uniform
  int lane = threadIdx.x & 63;
  int e4 = lane >> 4, l16 = lane & 15;
  int h = l16 >> 2;
  const uint4* K4 = reinterpret_cast<const uint4*>(K8);
  const uint4* V4 = reinterpret_cast<const uint4*>(V8);

  float4 qe0 = {0, 0, 0, 0}, qe1 = qe0, qe2 = qe0, qe3 = qe0;
  float dq0 = 0.f, dq1 = 0.f, dq2 = 0.f, dq3 = 0.f, dq4 = 0.f;
  int dcount = 0;
  if (node < n) {
    const float4* Q4 = reinterpret_cast<const float4*>(Q);
    const float4* S4 = reinterpret_cast<const float4*>(QS5);
    float4 qv0 = Q4[(size_t)node * 64 + l16 * 4 + 0];
    float4 qv1 = Q4[(size_t)node * 64 + l16 * 4 + 1];
    float4 qv2 = Q4[(size_t)node * 64 + l16 * 4 + 2];
    float4 qv3 = Q4[(size_t)node * 64 + l16 * 4 + 3];
    int gr = batch[node] / 5;
    float4 s0 = S4[gr * 64 + l16 * 4 + 0];
    float4 s1 = S4[gr * 64 + l16 * 4 + 1];
    float4 s2 = S4[gr * 64 + l16 * 4 + 2];
    float4 s3 = S4[gr * 64 + l16 * 4 + 3];
    qe0.x = qv0.x + s0.x; qe0.y = qv0.y + s0.y; qe0.z = qv0.z + s0.z; qe0.w = qv0.w + s0.w;
    qe1.x = qv1.x + s1.x; qe1.y = qv1.y + s1.y; qe1.z = qv1.z + s1.z; qe1.w = qv1.w + s1.w;
    qe2.x = qv2.x + s2.x; qe2.y = qv2.y + s2.y; qe2.z = qv2.z + s2.z; qe2.w = qv2.w + s2.w;
    qe3.x = qv3.x + s3.x; qe3.y = qv3.y + s3.y; qe3.z = qv3.z + s3.z; qe3.w = qv3.w + s3.w;
#pragma unroll
    for (int g = 0; g < 5; g++) {
      float4 w0 = S4[g * 64 + l16 * 4 + 0];
      float4 w1 = S4[g * 64 + l16 * 4 + 1];
      float4 w2 = S4[g * 64 + l16 * 4 + 2];
      float4 w3 = S4[g * 64 + l16 * 4 + 3];
      float d = qv0.x * w0.x + qv0.y * w0.y + qv0.z * w0.z + qv0.w * w0.w +
                qv1.x * w1.x + qv1.y * w1.y + qv1.z * w1.z + qv1.w * w1.w +
                qv2.x * w2.x + qv2.y * w2.y + qv2.z * w2.z + qv2.w * w2.w +
                qv3.x * w3.x + qv3.y * w3.y + qv3.z * w3.z + qv3.w * w3.w;
      d += __shfl_xor(d, 1);
      d += __shfl_xor(d, 2);
      if (g == 0) dq0 = d;
      else if (g == 1) dq1 = d;
      else if (g == 2) dq2 = d;
      else if (g == 3) dq3 = d;
      else dq4 = d;
    }
    dcount = deg[node];
    if (dcount > PAD) dcount = PAD;
  }
  const int* myCol = colPad + (size_t)node * PAD;
  float sumExp = 0.f;
  float4 ac0 = {0, 0, 0, 0}, ac1 = ac0, ac2 = ac0, ac3 = ac0;
  bool lead = (l16 & 3) == 0;

#define EDGE4(MBASE, MASKED)                                                   \
  {                                                                            \
    int idx = (MBASE) + e4;                                                    \
    bool valid = MASKED ? (idx < dcount) : true;                               \
    int cc = valid ? myCol[idx] : 0;                                           \
    int c = cc & 0xFFFFFF, gc = cc >> 24;                                      \
    uint4 kr = K4[(size_t)c * 16 + l16];                                       \
    uint4 vr = {0, 0, 0, 0};                                                   \
    if (DO_AGG) vr = V4[(size_t)c * 16 + l16];                                 \
    float4 kd0 = fp8x4_dec(kr.x), kd1 = fp8x4_dec(kr.y);                       \
    float4 kd2 = fp8x4_dec(kr.z), kd3 = fp8x4_dec(kr.w);                       \
    float p0 = qe0.x * kd0.x + qe0.y * kd0.y + qe0.z * kd0.z + qe0.w * kd0.w;  \
    float p1 = qe1.x * kd1.x + qe1.y * kd1.y + qe1.z * kd1.z + qe1.w * kd1.w;  \
    float p2 = qe2.x * kd2.x + qe2.y * kd2.y + qe2.z * kd2.z + qe2.w * kd2.w;  \
    float p3 = qe3.x * kd3.x + qe3.y * kd3.y + qe3.z * kd3.z + qe3.w * kd3.w;  \
    float p = (p0 + p1) + (p2 + p3);                                           \
    p += __shfl_xor(p, 1);                                                     \
    p += __shfl_xor(p, 2);                                                     \
    float dv = (gc == 0) ? dq0 : (gc == 1) ? dq1 : (gc == 2) ? dq2             \
               : (gc == 3) ? dq3 : dq4;                                        \
    float sv = (p + dv) * (1.f / 24.f);                                        \
    sv = (sv >= 0.f) ? sv : 0.2f * sv;                                         \
    float ev = __expf(sv);                                                     \
    if (MASKED && !valid) ev = 0.f;                                            \
    if (lead) sumExp += ev;                                                    \
    if (DO_AGG) {                                                              \
      float4 vd0 = fp8x4_dec(vr.x), vd1 = fp8x4_dec(vr.y);                     \
      float4 vd2 = fp8x4_dec(vr.z), vd3 = fp8x4_dec(vr.w);                     \
      ac0.x += ev * vd0.x; ac0.y += ev * vd0.y; ac0.z += ev * vd0.z;           \
      ac0.w += ev * vd0.w;                                                     \
      ac1.x += ev * vd1.x; ac1.y += ev * vd1.y; ac1.z += ev * vd1.z;           \
      ac1.w += ev * vd1.w;                                                     \
      ac2.x += ev * vd2.x; ac2.y += ev * vd2.y; ac2.z += ev * vd2.z;           \
      ac2.w += ev * vd2.w;                                                     \
      ac3.x += ev * vd3.x; ac3.y += ev * vd3.y; ac3.z += ev * vd3.z;           \
      ac3.w += ev * vd3.w;                                                     \
    }                                                                          \
  }

  int m = 0;
  for (; m + 8 <= dcount; m += 8) {
    EDGE4(m, false)
    EDGE4(m + 4, false)
  }
  for (; m < dcount; m += 4) {
    EDGE4(m, true)
  }
#undef EDGE4

  // combine across the 4 edge-groups
  sumExp += __shfl_xor(sumExp, 16);
  sumExp += __shfl_xor(sumExp, 32);
  if (DO_AGG && node < n) {
    ac0.x += __shfl_xor(ac0.x, 16); ac0.x += __shfl_xor(ac0.x, 32);
    ac0.y += __shfl_xor(ac0.y, 16); ac0.y += __shfl_xor(ac0.y, 32);
    ac0.z += __shfl_xor(ac0.z, 16); ac0.z += __shfl_xor(ac0.z, 32);
    ac0.w += __shfl_xor(ac0.w, 16); ac0.w += __shfl_xor(ac0.w, 32);
    ac1.x += __shfl_xor(ac1.x, 16); ac1.x += __shfl_xor(ac1.x, 32);
    ac1.y += __shfl_xor(ac1.y, 16); ac1.y += __shfl_xor(ac1.y, 32);
    ac1.z += __shfl_xor(ac1.z, 16); ac1.z += __shfl_xor(ac1.z, 32);
    ac1.w += __shfl_xor(ac1.w, 16); ac1.w += __shfl_xor(ac1.w, 32);
    ac2.x += __shfl_xor(ac2.x, 16); ac2.x += __shfl_xor(ac2.x, 32);
    ac2.y += __shfl_xor(ac2.y, 16); ac2.y += __shfl_xor(ac2.y, 32);
    ac2.z += __shfl_xor(ac2.z, 16); ac2.z += __shfl_xor(ac2.z, 32);
    ac2.w += __shfl_xor(ac2.w, 16); ac2.w += __shfl_xor(ac2.w, 32);
    ac3.x += __shfl_xor(ac3.x, 16); ac3.x += __shfl_xor(ac3.x, 32);
    ac3.y += __shfl_xor(ac3.y, 16); ac3.y += __shfl_xor(ac3.y, 32);
    ac3.z += __shfl_xor(ac3.z, 16); ac3.z += __shfl_xor(ac3.z, 32);
    ac3.w += __shfl_xor(ac3.w, 16); ac3.w += __shfl_xor(ac3.w, 32);
    if (e4 == 0) {
      ushort4* A4 = reinterpret_cast<ushort4*>(aggb);
      ushort4 b0, b1, b2, b3;
      b0.x = f2b(ac0.x); b0.y = f2b(ac0.y); b0.z = f2b(ac0.z); b0.w = f2b(ac0.w);
      b1.x = f2b(ac1.x); b1.y = f2b(ac1.y); b1.z = f2b(ac1.z); b1.w = f2b(ac1.w);
      b2.x = f2b(ac2.x); b2.y = f2b(ac2.y); b2.z = f2b(ac2.z); b2.w = f2b(ac2.w);
      b3.x = f2b(ac3.x); b3.y = f2b(ac3.y); b3.z = f2b(ac3.z); b3.w = f2b(ac3.w);
      A4[(size_t)node * 64 + l16 * 4 + 0] = b0;
      A4[(size_t)node * 64 + l16 * 4 + 1] = b1;
      A4[(size_t)node * 64 + l16 * 4 + 2] = b2;
      A4[(size_t)node * 64 + l16 * 4 + 3] = b3;
    }
  }
  __shared__ float red[4][4];
  int w = threadIdx.x >> 6;
  if (e4 == 0 && lead) red[w][h] = sumExp;
  __syncthreads();
  if (threadIdx.x < 4) {
    float t = red[0][threadIdx.x] + red[1][threadIdx.x] + red[2][threadIdx.x] +
              red[3][threadIdx.x];
    atomicAdd(&sums[threadIdx.x], t);
  }
}

// ---------------- layer-2: agg for node 0 only ------------------------------
__global__ __launch_bounds__(64) void node0_agg_kernel(
    const int* __restrict__ deg, const int* __restrict__ colPad,
    const int* __restrict__ batch, const float* __restrict__ Q,
    const unsigned int* __restrict__ K8, const unsigned int* __restrict__ V8,
    const float* __restrict__ QS5, const float* __restrict__ sums,
    float* __restrict__ agg0) {
  int lane = threadIdx.x;
  int head = lane >> 4;
  float4 q = reinterpret_cast<const float4*>(Q)[lane];
  int gr = batch[0] / 5;
  float4 qs = reinterpret_cast<const float4*>(QS5)[gr * 64 + lane];
  float4 qe = {q.x + qs.x, q.y + qs.y, q.z + qs.z, q.w + qs.w};
  float dq0 = 0.f, dq1 = 0.f, dq2 = 0.f, dq3 = 0.f, dq4 = 0.f;
#pragma unroll
  for (int g = 0; g < 5; g++) {
    float4 w = reinterpret_cast<const float4*>(QS5)[g * 64 + lane];
    float d = q.x * w.x + q.y * w.y + q.z * w.z + q.w * w.w;
    d += __shfl_xor(d, 1);
    d += __shfl_xor(d, 2);
    d += __shfl_xor(d, 4);
    d += __shfl_xor(d, 8);
    if (g == 0) dq0 = d;
    else if (g == 1) dq1 = d;
    else if (g == 2) dq2 = d;
    else if (g == 3) dq3 = d;
    else dq4 = d;
  }
  float4 acc = {0.f, 0.f, 0.f, 0.f};
  int dcount = deg[0];
  if (dcount > PAD) dcount = PAD;
  for (int m = 0; m < dcount; m++) {
    int cc = colPad[m];
    int c = cc & 0xFFFFFF, gc = cc >> 24;
    float4 kd = fp8x4_dec(K8[(size_t)c * 64 + lane]);
    float p = qe.x * kd.x + qe.y * kd.y + qe.z * kd.z + qe.w * kd.w;
    p += __shfl_xor(p, 1);
    p += __shfl_xor(p, 2);
    p += __shfl_xor(p, 4);
    p += __shfl_xor(p, 8);
    float dqv = (gc == 0) ? dq0
                : (gc == 1) ? dq1
                : (gc == 2) ? dq2
                : (gc == 3) ? dq3 : dq4;
    float v = (p + dqv) * (1.f / 24.f);
    v = (v >= 0.f) ? v : 0.2f * v;
    float ev = __expf(v);
    float4 vd = fp8x4_dec(V8[(size_t)c * 64 + lane]);
    acc.x += ev * vd.x;
    acc.y += ev * vd.y;
    acc.z += ev * vd.z;
    acc.w += ev * vd.w;
  }
  float invS = 1.f / sums[head];
  acc.x *= invS; acc.y *= invS; acc.z *= invS; acc.w *= invS;
  reinterpret_cast<float4*>(agg0)[lane] = acc;
}

// x1 = ((agg0 @ Wo2 + bo2 + x[0]) @ W1 + b1), 1024 threads, 4-way k-split
__global__ __launch_bounds__(1024) void final_head_kernel(
    const float* __restrict__ agg0, const float* __restrict__ Wo2,
    const float* __restrict__ bo2, const float* __restrict__ x,
    const float* __restrict__ W1, const float* __restrict__ b1,
    float* __restrict__ x1) {
  __shared__ float a0[256];
  __shared__ float t1[256];
  __shared__ float part[4][256];
  int tid = threadIdx.x;
  int j = tid & 255, s = tid >> 8;
  if (tid < 256) a0[tid] = agg0[tid];
  __syncthreads();
  float acc = 0.f;
#pragma unroll 8
  for (int k = s * 64; k < s * 64 + 64; k++) acc += a0[k] * Wo2[k * 256 + j];
  part[s][j] = acc;
  __syncthreads();
  if (tid < 256)
    t1[tid] = part[0][tid] + part[1][tid] + part[2][tid] + part[3][tid] +
              bo2[tid] + x[tid];
  __syncthreads();
  float acc2 = 0.f;
#pragma unroll 8
  for (int k = s * 64; k < s * 64 + 64; k++) acc2 += t1[k] * W1[k * 256 + j];
  part[s][j] = acc2;
  __syncthreads();
  if (tid < 256)
    x1[tid] = part[0][tid] + part[1][tid] + part[2][tid] + part[3][tid] +
              b1[tid];
}

// ---------------- AO[b] = softmax_t(x1 . tok[b,t] / 16) @ tok[b] ------------
__global__ __launch_bounds__(256) void attn_out_kernel(
    const float* __restrict__ x1g, const float* __restrict__ tok,
    float* __restrict__ AO) {
  int b = blockIdx.x;
  int tid = threadIdx.x;
  int wave = tid >> 6, lane = tid & 63;
  int sub = lane >> 4, l16 = lane & 15;
  __shared__ float x1s[256];
  __shared__ float scs[256];
  __shared__ float red[256];
  __shared__ float wgt[256];
  x1s[tid] = x1g[tid];
  __syncthreads();
  const float4* xv4 = reinterpret_cast<const float4*>(x1s);
  for (int it = 0; it < 16; it++) {
    int row = wave * 64 + it * 4 + sub;
    const float4* tr =
        reinterpret_cast<const float4*>(tok + (size_t)(b * 256 + row) * 256);
    float sc = 0.f;
#pragma unroll
    for (int q = 0; q < 4; q++) {
      float4 v = tr[l16 + q * 16];
      float4 xv = xv4[l16 + q * 16];
      sc += v.x * xv.x + v.y * xv.y + v.z * xv.z + v.w * xv.w;
    }
    sc += __shfl_xor(sc, 1);
    sc += __shfl_xor(sc, 2);
    sc += __shfl_xor(sc, 4);
    sc += __shfl_xor(sc, 8);
    if (l16 == 0) scs[row] = sc * (1.f / 16.f);
  }
  __syncthreads();
  float sc = scs[tid];
  red[tid] = sc;
  __syncthreads();
  for (int off = 128; off; off >>= 1) {
    if (tid < off) red[tid] = fmaxf(red[tid], red[tid + off]);
    __syncthreads();
  }
  float mx = red[0];
  __syncthreads();
  float ex = expf(sc - mx);
  red[tid] = ex;
  __syncthreads();
  for (int off = 128; off; off >>= 1) {
    if (tid < off) red[tid] += red[tid + off];
    __syncthreads();
  }
  wgt[tid] = ex / red[0];
  __syncthreads();
  float acc = 0.f;
#pragma unroll 4
  for (int k = 0; k < 256; k++)
    acc += wgt[k] * tok[(size_t)(b * 256 + k) * 256 + tid];
  AO[b * 256 + tid] = acc;
}

// ---------------- final: partial[s][j] = sum_{k in slice s} AO[k]*Wout[k][j] -
__global__ __launch_bounds__(256) void final_y_kernel(
    const float* __restrict__ AO, const float* __restrict__ Wout,
    float* __restrict__ partial) {
  int s = blockIdx.x;  // 0..15, 80 rows each
  int j = threadIdx.x;
  __shared__ float a[80];
  if (threadIdx.x < 80) a[threadIdx.x] = AO[s * 80 + threadIdx.x];
  __syncthreads();
  const float* W = Wout + (size_t)s * 80 * 256;
  float acc = 0.f;
#pragma unroll 8
  for (int k = 0; k < 80; k++) acc += a[k] * W[k * 256 + j];
  partial[s * 256 + j] = acc;
}

// ---------------- out: y = reduce(partial)+bout; o = y@W3 + b3; 25 copies ---
__global__ __launch_bounds__(256) void final_out2_kernel(
    const float* __restrict__ partial, const float* __restrict__ bout,
    const float* __restrict__ W3, const float* __restrict__ b3,
    float* __restrict__ out) {
  __shared__ float y[256];
  int j = threadIdx.x;
  float acc = bout[j];
#pragma unroll
  for (int s = 0; s < 16; s++) acc += partial[s * 256 + j];
  y[j] = acc;
  __syncthreads();
  int t = blockIdx.x * 256 + j;
  float o = b3[t];
#pragma unroll 8
  for (int k = 0; k < 256; k++) o += y[k] * W3[k * 1024 + t];
  for (int g = 0; g < 25; g++) out[(size_t)g * 1024 + t] = o;
}

extern "C" void kernel_launch(void* const* d_in, const int* in_sizes, int n_in,
                              void* d_out, int out_size, void* d_ws,
                              size_t ws_size, hipStream_t stream) {
  const int* concept_ids = (const int*)d_in[0];
  const int* edge_index = (const int*)d_in[1];
  const float* sent = (const float*)d_in[3];
  const float* tokemb = (const float*)d_in[4];
  const int* batch = (const int*)d_in[5];
  const float* ent = (const float*)d_in[6];
  const float* Wq = (const float*)d_in[7];
  const float* bq = (const float*)d_in[8];
  const float* Wk = (const float*)d_in[9];
  const float* bk = (const float*)d_in[10];
  const float* Wv = (const float*)d_in[11];
  const float* bv = (const float*)d_in[12];
  const float* Ws = (const float*)d_in[13];
  const float* bs = (const float*)d_in[14];
  const float* Wo = (const float*)d_in[15];
  const float* bo = (const float*)d_in[16];
  const float* W1 = (const float*)d_in[17];
  const float* b1 = (const float*)d_in[18];
  const float* W2 = (const float*)d_in[19];
  const float* b2 = (const float*)d_in[20];
  const float* W3 = (const float*)d_in[21];
  const float* b3 = (const float*)d_in[22];
  const float* Wout = (const float*)d_in[23];
  const float* bout = (const float*)d_in[24];
  float* out = (float*)d_out;

  float* ws = (float*)d_ws;
  size_t off_ = 0;
  auto alloc = [&](size_t n) {
    float* p = ws + off_;
    off_ += n;
    return p;
  };
  float* x = alloc((size_t)NNODES * DM);
  float* x2 = alloc((size_t)NNODES * DM);
  float* Qf = alloc((size_t)NNODES * DM);
  unsigned short* xb = (unsigned short*)alloc((size_t)NNODES * DM / 2);
  unsigned short* aggb = (unsigned short*)alloc((size_t)NNODES * DM / 2);
  unsigned char* K8 = (unsigned char*)alloc((size_t)NNODES * DM / 4);
  unsigned char* V8 = (unsigned char*)alloc((size_t)NNODES * DM / 4);
  unsigned short* WT = (unsigned short*)alloc(12 * 65536 / 2);
  unsigned short* W2T = (unsigned short*)alloc(262144 / 2);
  unsigned short* tokb = (unsigned short*)alloc(1280 * 1024 / 2);
  float* tok = alloc(1280 * 256);
  float* QS5all = alloc(3 * 5 * 256);
  float* sums = alloc(16);
  float* agg0 = alloc(256);
  float* x1 = alloc(256);
  float* AO = alloc(1280);
  float* partial = alloc(16 * 256);
  int* deg = (int*)alloc(NNODES);
  int* colPad = (int*)alloc((size_t)NNODES * PAD);

  // prep (all layer-invariant)
  gather_kernel<<<5000, 256, 0, stream>>>(concept_ids, ent, x, xb, NNODES);
  wtrans12_kernel<<<3072, 256, 0, stream>>>(Wq, Wk, Wv, Wo, WT);
  w2t_kernel<<<1024, 256, 0, stream>>>(W2, W2T);
  tokconv_kernel<<<1280, 256, 0, stream>>>(tokemb, tokb);
  hipMemsetAsync(deg, 0, NNODES * sizeof(int), stream);
  fill_kernel<<<(NEDGES + 255) / 256, 256, 0, stream>>>(edge_index, batch, deg,
                                                        colPad, NEDGES);
  {
    dim3 g(5, 3);
    qs5all_kernel<<<g, 256, 0, stream>>>(sent, Ws, bs, QS5all);
  }
  hipMemsetAsync(sums, 0, 12 * sizeof(float), stream);

  float* xin = x;
  float* xout = x2;
  for (int l = 0; l < 3; l++) {
    unsigned short* WoT = WT + (size_t)(l * 4 + 3) * 65536;
    {
      dim3 g(12, (NNODES + 63) / 64);
      qkv_gemm_kernel<<<g, 256, 0, stream>>>(
          xb, WT + (size_t)(l * 4) * 65536, bq + l * DM, bk + l * DM,
          bv + l * DM, Qf, K8, V8, NNODES);
    }
    if (l < 2) {
      fused_edge_kernel<1><<<5000, 256, 0, stream>>>(
          deg, colPad, batch, Qf, (const unsigned int*)K8,
          (const unsigned int*)V8, QS5all + l * 1280, sums + l * 4, aggb,
          NNODES);
      rescale_wo_kernel<<<256, 256, 0, stream>>>(WoT, sums + l * 4);
      dim3 g(4, (NNODES + 63) / 64);
      gemm_bf16_kernel<<<g, 256, 0, stream>>>(aggb, WoT, bo + l * DM, xin,
                                              xout, xb, NNODES, 256);
      float* tmp = xin;
      xin = xout;
      xout = tmp;
    } else {
      fused_edge_kernel<0><<<5000, 256, 0, stream>>>(
          deg, colPad, batch, Qf, (const unsigned int*)K8,
          (const unsigned int*)V8, QS5all + l * 1280, sums + l * 4, nullptr,
          NNODES);
      node0_agg_kernel<<<1, 64, 0, stream>>>(
          deg, colPad, batch, Qf, (const unsigned int*)K8,
          (const unsigned int*)V8, QS5all + l * 1280, sums + l * 4, agg0);
      final_head_kernel<<<1, 1024, 0, stream>>>(agg0, Wo + (size_t)2 * 65536,
                                                bo + 2 * DM, xin, W1, b1, x1);
    }
  }

  // tok = token_embedding @ W2 + b2 via MFMA (M=1280, K=1024)
  {
    dim3 g(4, 1280 / 64);
    gemm_bf16_kernel<<<g, 256, 0, stream>>>(tokb, W2T, b2, nullptr, tok,
                                            nullptr, 1280, 1024);
  }
  attn_out_kernel<<<5, 256, 0, stream>>>(x1, tok, AO);
  final_y_kernel<<<16, 256, 0, stream>>>(AO, Wout, partial);
  final_out2_kernel<<<4, 256, 0, stream>>>(partial, bout, W3, b3, out);
}